// Round 27
// baseline (94.410 us; speedup 1.0000x reference)
//
#include <hip/hip_runtime.h>
#include <hip/hip_bf16.h>
#include <math.h>

#define BN 32
#define XLEN 1024
#define COLS 512
#define ROWS (BN * XLEN)   // 32768
#define STAB 1e-15

typedef float v2f __attribute__((ext_vector_type(2)));

#define HW_EXP2(x) __builtin_amdgcn_exp2f(x)
#define HW_LOG2(x) __builtin_amdgcn_logf(x)
#define HW_RCP(x)  __builtin_amdgcn_rcpf(x)

// ---------------------------------------------------------------------------
// DPP rotate helpers: row_ror:N within 16-lane rows, VALU pipe (round 21).
// ---------------------------------------------------------------------------
template <int CTRL>
__device__ __forceinline__ float dpp_rot_f32(float v) {
  return __int_as_float(__builtin_amdgcn_mov_dpp(
      __float_as_int(v), CTRL, 0xF, 0xF, false));
}
template <int CTRL>
__device__ __forceinline__ double dpp_rot_f64(double v) {
  const unsigned long long u = __double_as_longlong(v);
  const int lo = __builtin_amdgcn_mov_dpp((int)(u & 0xFFFFFFFFull),
                                          CTRL, 0xF, 0xF, false);
  const int hi = __builtin_amdgcn_mov_dpp((int)(u >> 32),
                                          CTRL, 0xF, 0xF, false);
  return __longlong_as_double(((unsigned long long)(unsigned)hi << 32) |
                              (unsigned)lo);
}
#define ROR8 0x128
#define ROR4 0x124
#define ROR2 0x122
#define ROR1 0x121

__device__ __forceinline__ float dpp_max16_f32(float v) {
  v = fmaxf(v, dpp_rot_f32<ROR8>(v));
  v = fmaxf(v, dpp_rot_f32<ROR4>(v));
  v = fmaxf(v, dpp_rot_f32<ROR2>(v));
  v = fmaxf(v, dpp_rot_f32<ROR1>(v));
  return v;
}
__device__ __forceinline__ float dpp_min16_f32(float v) {
  v = fminf(v, dpp_rot_f32<ROR8>(v));
  v = fminf(v, dpp_rot_f32<ROR4>(v));
  v = fminf(v, dpp_rot_f32<ROR2>(v));
  v = fminf(v, dpp_rot_f32<ROR1>(v));
  return v;
}
__device__ __forceinline__ double dpp_sum16_f64(double v) {
  v += dpp_rot_f64<ROR8>(v);
  v += dpp_rot_f64<ROR4>(v);
  v += dpp_rot_f64<ROR2>(v);
  v += dpp_rot_f64<ROR1>(v);
  return v;
}

// ---------------------------------------------------------------------------
// ONE launch, branch-disjoint producer/consumer:
//   blocks 0..31      : per-batch PCR solver. Resident from t=0, thread 0
//                       spins (s_sleep-throttled, acquire) on cnt[batch]
//                       until all 64 gaus blocks of its batch signaled, then
//                       solves with 256 threads x 4 elements in LDS.
//   blocks 32..2079   : gaus fit, BYTE-IDENTICAL numerics to round 24
//                       (best measured 24.27us, absmax 4096): 4 rows/wave,
//                       16 lanes/row, S-free normalize, DPP-16 reductions,
//                       f64 cross-lane tree (round-14 rule). After writing
//                       mu/sigma: syncthreads (drain) -> device release
//                       fence -> atomicAdd(cnt[batch]).
// vs round 18 (regalloc collapse, 4x): phases are DISJOINT branches here —
// VGPR = max(paths), not union; no thread runs both phases.
// Deterministic: solvers consume only finalized mu/sig; arrival order can't
// change values. 32 spinner blocks << 2048 block-slots -> no deadlock.
// ---------------------------------------------------------------------------
__global__ __launch_bounds__(256) void surf_fused_kernel(
    const float* __restrict__ x, const float* __restrict__ w_comp,
    float* __restrict__ mu_ws, float* __restrict__ sig_ws,
    unsigned* __restrict__ cnt, float* __restrict__ out) {
  __shared__ float As[XLEN], Bs[XLEN], Cs[XLEN], Ds[XLEN];

  if (blockIdx.x < BN) {
    // ------------------- consumer: PCR solver for one batch ---------------
    const int batch = blockIdx.x;
    if (threadIdx.x == 0) {
      while (__hip_atomic_load(&cnt[batch], __ATOMIC_ACQUIRE,
                               __HIP_MEMORY_SCOPE_AGENT) < 64u) {
        __builtin_amdgcn_s_sleep(32);
      }
    }
    __syncthreads();
    __threadfence();   // acquire: invalidate stale cached mu/sig

    const int base = batch * XLEN;
    const float w = w_comp[0];
    const float offf = -2.0f * w;
    const int t = threadIdx.x;
#pragma unroll
    for (int q = 0; q < 4; ++q) {
      const int i = t + 256 * q;
      const float sr = 1.0f / sig_ws[base + i];     // f32, matches reference
      const float mainw = (i == 0 || i == XLEN - 1) ? (2.0f * w) : (4.0f * w);
      As[i] = (i == 0) ? 0.0f : offf;
      Cs[i] = (i == XLEN - 1) ? 0.0f : offf;
      Bs[i] = mainw + sr;
      Ds[i] = mu_ws[base + i] * sr;
    }
    __syncthreads();

    for (int s = 1; s < XLEN; s <<= 1) {
      float na[4], nb[4], nc[4], nd[4];
#pragma unroll
      for (int q = 0; q < 4; ++q) {
        const int i = t + 256 * q;
        const float ai = As[i], bi = Bs[i], ci = Cs[i], di = Ds[i];
        float am = 0.0f, cm = 0.0f, dm = 0.0f, rm = 0.0f;
        float ap = 0.0f, cp = 0.0f, dp = 0.0f, rp = 0.0f;
        if (i >= s) {
          am = As[i - s]; cm = Cs[i - s]; dm = Ds[i - s];
          rm = HW_RCP(Bs[i - s]);
        }
        if (i + s < XLEN) {
          ap = As[i + s]; cp = Cs[i + s]; dp = Ds[i + s];
          rp = HW_RCP(Bs[i + s]);
        }
        const float k1 = ai * rm;   // rm/rp are 0 when guarded out
        const float k2 = ci * rp;
        nb[q] = bi - k1 * cm - k2 * ap;
        nd[q] = di - k1 * dm - k2 * dp;
        na[q] = -k1 * am;
        nc[q] = -k2 * cp;
      }
      __syncthreads();
#pragma unroll
      for (int q = 0; q < 4; ++q) {
        const int i = t + 256 * q;
        As[i] = na[q]; Bs[i] = nb[q]; Cs[i] = nc[q]; Ds[i] = nd[q];
      }
      __syncthreads();
    }

#pragma unroll
    for (int q = 0; q < 4; ++q) {
      const int i = t + 256 * q;
      out[base + i] = Ds[i] / Bs[i];
    }
    return;
  }

  // ------------------- producer: gaus fit (round-24 numerics) -------------
  const int bid  = blockIdx.x - BN;
  const int lane = threadIdx.x & 63;
  const int wid  = threadIdx.x >> 6;   // wave 0..3 in block
  const int sub  = lane & 15;          // lane within row-group
  const int row  = bid * 16 + wid * 4 + (lane >> 4);

  const v2f* rp2 = (const v2f*)(x + (size_t)row * COLS);
  v2f ve[16];
#pragma unroll
  for (int j = 0; j < 8; ++j) {
    ve[2 * j]     = rp2[32 * j + 2 * sub];
    ve[2 * j + 1] = rp2[32 * j + 2 * sub + 1];
  }

  v2f mx2 = ve[0], xn2 = ve[0];
#pragma unroll
  for (int k = 1; k < 16; ++k) {
    mx2 = __builtin_elementwise_max(mx2, ve[k]);
    xn2 = __builtin_elementwise_min(xn2, ve[k]);
  }
  const float mx = dpp_max16_f32(fmaxf(mx2.x, mx2.y));
  const float xn = dpp_min16_f32(fminf(xn2.x, xn2.y));

  // S-free normalize (round-24 algebra): pn = (e - emin)/(1 - emin) + 0.001
  const float LOG2E = 1.44269504089f;
  const float mxs  = mx * LOG2E;
  const float emin = HW_EXP2(fmaf(xn, LOG2E, -mxs));
  const float CA   = 1.0f / (1.0f - emin);
  const float CB   = fmaf(-emin, CA, 0.001f);
  const v2f L2E2 = {LOG2E, LOG2E};
  const v2f NMXS = {-mxs, -mxs};
  const v2f CA2 = {CA, CA}, CB2 = {CB, CB};

  const float bb = (float)(4 * sub) * (1.0f / 512.0f);
  v2f u0 = {0, 0}, u1 = {0, 0}, u2 = {0, 0}, u3 = {0, 0}, u4 = {0, 0};
  v2f w0 = {0, 0}, w1 = {0, 0}, w2 = {0, 0};

#define GF_PAIR(j, h)                                                         \
  {                                                                           \
    const int   k   = 2 * (j) + (h);                                          \
    const float off = (float)(64 * (j) + 2 * (h)) * (1.0f / 512.0f);          \
    const v2f xh = {bb + off, bb + off + 0.001953125f};                       \
    const v2f xs = __builtin_elementwise_fma(ve[k], L2E2, NMXS);              \
    v2f e;                                                                    \
    e.x = HW_EXP2(xs.x);                                                      \
    e.y = HW_EXP2(xs.y);                                                      \
    const v2f pn = __builtin_elementwise_fma(e, CA2, CB2);                    \
    v2f l2;                                                                   \
    l2.x = HW_LOG2(pn.x);                                                     \
    l2.y = HW_LOG2(pn.y);                                                     \
    const v2f y2  = pn * pn;                                                  \
    const v2f y2l = y2 * l2;                                                  \
    const v2f x2  = xh * xh;                                                  \
    const v2f x3  = x2 * xh;                                                  \
    const v2f x4  = x2 * x2;                                                  \
    u0 += y2;                                                                 \
    u1 = __builtin_elementwise_fma(xh, y2, u1);                               \
    u2 = __builtin_elementwise_fma(x2, y2, u2);                               \
    u3 = __builtin_elementwise_fma(x3, y2, u3);                               \
    u4 = __builtin_elementwise_fma(x4, y2, u4);                               \
    w0 += y2l;                                                                \
    w1 = __builtin_elementwise_fma(xh, y2l, w1);                              \
    w2 = __builtin_elementwise_fma(x2, y2l, w2);                              \
  }

#pragma unroll
  for (int j = 0; j < 8; ++j) {
    GF_PAIR(j, 0)
    GF_PAIR(j, 1)
  }
#undef GF_PAIR

  // per-lane exact f64 hadd, then 16-lane DPP rotate-reduce in f64
  // (f64 REQUIRED — round-14 lesson: the fit formula amplifies sum error)
  const double d0 = dpp_sum16_f64((double)u0.x + (double)u0.y);
  const double d1 = dpp_sum16_f64((double)u1.x + (double)u1.y);
  const double d2 = dpp_sum16_f64((double)u2.x + (double)u2.y);
  const double d3 = dpp_sum16_f64((double)u3.x + (double)u3.y);
  const double d4 = dpp_sum16_f64((double)u4.x + (double)u4.y);
  const double e0 = dpp_sum16_f64((double)w0.x + (double)w0.y);
  const double e1 = dpp_sum16_f64((double)w1.x + (double)w1.y);
  const double e2 = dpp_sum16_f64((double)w2.x + (double)w2.y);

  if (sub == 0) {   // lanes 0,16,32,48 — one per row
    const double LN2D = 0.6931471805599453;
    const double s_y2    = d0;
    const double s_xy2   = d1 * 512.0;
    const double s_x2y2  = d2 * 262144.0;            // 512^2
    const double s_x3y2  = d3 * 134217728.0;         // 512^3
    const double s_x4y2  = d4 * 68719476736.0;       // 512^4
    const double s_y2l   = e0 * LN2D;
    const double s_xy2l  = (e1 * 512.0) * LN2D;
    const double s_x2y2l = (e2 * 262144.0) * LN2D;
    const double A2 = s_x2y2 * s_x2y2;
    double b_num = A2 * s_xy2l - s_y2 * s_x4y2 * s_xy2l
                 + s_xy2 * s_x4y2 * s_y2l + s_y2 * s_x3y2 * s_x2y2l
                 - s_x2y2 * s_x3y2 * s_y2l - s_xy2 * s_x2y2 * s_x2y2l;
    double c_num = s_x2y2l * s_xy2 * s_xy2 - s_xy2l * s_xy2 * s_x2y2
                 - s_x3y2 * s_y2l * s_xy2 + s_y2l * A2
                 - s_y2 * s_x2y2l * s_x2y2 + s_y2 * s_x3y2 * s_xy2l;
    if (fabs(c_num) < STAB) {
      c_num = (c_num > 0.0) ? STAB : ((c_num < 0.0) ? -STAB : 0.0);
    }
    const double mu = -b_num / (2.0 * c_num);
    const double c_din = s_x4y2 * s_xy2 * s_xy2
                       - 2.0 * s_xy2 * s_x2y2 * s_x3y2 + s_x2y2 * A2
                       - s_y2 * s_x4y2 * s_x2y2 + s_y2 * s_x3y2 * s_x3y2;
    double sigma = -0.5 * c_din / c_num;
    if (sigma < 1.0) sigma = 1.0;  // NaN stays NaN, matching jnp.where
    mu_ws[row]  = (float)mu;
    sig_ws[row] = (float)sigma;
  }

  // signal: this block's 16 rows are final
  __syncthreads();                     // drains this block's stores
  if (threadIdx.x == 0) {
    __threadfence();                   // device-scope release
    atomicAdd(&cnt[bid >> 6], 1u);     // 64 gaus blocks per batch
  }
}

extern "C" void kernel_launch(void* const* d_in, const int* in_sizes, int n_in,
                              void* d_out, int out_size, void* d_ws, size_t ws_size,
                              hipStream_t stream) {
  const float* x      = (const float*)d_in[0];
  const float* w_comp = (const float*)d_in[1];
  float* out = (float*)d_out;

  float* mu_ws  = (float*)d_ws;
  float* sig_ws = mu_ws + ROWS;
  unsigned* cnt = (unsigned*)(sig_ws + ROWS);

  // counters must start at 0 every call (d_ws is poisoned only once)
  hipMemsetAsync((void*)cnt, 0, BN * sizeof(unsigned), stream);
  surf_fused_kernel<<<BN + ROWS / 16, 256, 0, stream>>>(
      x, w_comp, mu_ws, sig_ws, cnt, out);
}

// Round 28
// 24.281 us; speedup vs baseline: 3.8882x; 3.8882x over previous
//
#include <hip/hip_runtime.h>
#include <hip/hip_bf16.h>
#include <math.h>

#define BN 32
#define XLEN 1024
#define COLS 512
#define ROWS (BN * XLEN)   // 32768
#define STAB 1e-15

typedef float v2f __attribute__((ext_vector_type(2)));

// hardware transcendentals via AMDGCN builtins (glibc-collision-free):
//   HW_EXP2(x) = v_exp_f32 = 2^x ;  HW_LOG2(x) = v_log_f32 = log2(x)
#define HW_EXP2(x) __builtin_amdgcn_exp2f(x)
#define HW_LOG2(x) __builtin_amdgcn_logf(x)
#define HW_RCP(x)  __builtin_amdgcn_rcpf(x)

// ---------------------------------------------------------------------------
// DPP rotate helpers: row_ror:N within 16-lane rows, VALU pipe (round 21).
// ---------------------------------------------------------------------------
template <int CTRL>
__device__ __forceinline__ float dpp_rot_f32(float v) {
  return __int_as_float(__builtin_amdgcn_mov_dpp(
      __float_as_int(v), CTRL, 0xF, 0xF, false));
}
template <int CTRL>
__device__ __forceinline__ double dpp_rot_f64(double v) {
  const unsigned long long u = __double_as_longlong(v);
  const int lo = __builtin_amdgcn_mov_dpp((int)(u & 0xFFFFFFFFull),
                                          CTRL, 0xF, 0xF, false);
  const int hi = __builtin_amdgcn_mov_dpp((int)(u >> 32),
                                          CTRL, 0xF, 0xF, false);
  return __longlong_as_double(((unsigned long long)(unsigned)hi << 32) |
                              (unsigned)lo);
}
#define ROR8 0x128
#define ROR4 0x124
#define ROR2 0x122
#define ROR1 0x121

__device__ __forceinline__ float dpp_max16_f32(float v) {
  v = fmaxf(v, dpp_rot_f32<ROR8>(v));
  v = fmaxf(v, dpp_rot_f32<ROR4>(v));
  v = fmaxf(v, dpp_rot_f32<ROR2>(v));
  v = fmaxf(v, dpp_rot_f32<ROR1>(v));
  return v;
}
__device__ __forceinline__ float dpp_min16_f32(float v) {
  v = fminf(v, dpp_rot_f32<ROR8>(v));
  v = fminf(v, dpp_rot_f32<ROR4>(v));
  v = fminf(v, dpp_rot_f32<ROR2>(v));
  v = fminf(v, dpp_rot_f32<ROR1>(v));
  return v;
}
__device__ __forceinline__ double dpp_sum16_f64(double v) {
  v += dpp_rot_f64<ROR8>(v);
  v += dpp_rot_f64<ROR4>(v);
  v += dpp_rot_f64<ROR2>(v);
  v += dpp_rot_f64<ROR1>(v);
  return v;
}

// ---------------------------------------------------------------------------
// Kernel 1: softmax -> min-max normalize -> weighted Gaussian fit.
// ROUND-24 CONFIGURATION RESTORED (best measured: 24.27 us, absmax 4096).
// KEY ALGEBRA: the softmax denominator S cancels exactly:
//   pn = (e - emin) / (1 - emin) + 0.001  — S never computed.
// Single pass: e = exp2(fma(x,log2e,-mxs)); pn = fma(e, CA, CB);
// l2 = v_log_f32(pn); packed f32 moments; ln2 folded into f64 log-sums.
// Structure: 4 rows/wave, 16 lanes/row, 16 packed pairs/lane, 4 waves per
// 256-thread block, grid 2048; all reductions via DPP row_ror (round 21).
// PRECISION NOTE (round-14): cross-lane reduction tree MUST be f64.
// FUSION NOTE (rounds 18 & 27): ANY single-kernel fusion of PCR (inline or
// branch-disjoint) collapses regalloc to 32 VGPR and spills ve[16] -> 4x.
// PIPELINE NOTE (round-20): 2-deep row pipelining costs occupancy, -5%.
// GENERATION NOTE (round-25): 2 rows/wave (more waves) regressed -6%.
// ---------------------------------------------------------------------------
__global__ __launch_bounds__(256) void gaus_fit_kernel(
    const float* __restrict__ x, float* __restrict__ mu_out,
    float* __restrict__ sig_out) {
  const int lane = threadIdx.x & 63;
  const int wid  = threadIdx.x >> 6;   // wave 0..3 in block
  const int sub  = lane & 15;          // lane within row-group
  const int row  = blockIdx.x * 16 + wid * 4 + (lane >> 4);

  // Each lane: 16 v2f loads (adjacent pairs merge to dwordx4); pair k=2j+h
  // covers cols 64*j + 4*sub + {2h, 2h+1}.
  const v2f* rp2 = (const v2f*)(x + (size_t)row * COLS);
  v2f ve[16];
#pragma unroll
  for (int j = 0; j < 8; ++j) {
    ve[2 * j]     = rp2[32 * j + 2 * sub];
    ve[2 * j + 1] = rp2[32 * j + 2 * sub + 1];
  }

  // packed min/max of raw x, then component + 16-lane DPP reduce
  v2f mx2 = ve[0], xn2 = ve[0];
#pragma unroll
  for (int k = 1; k < 16; ++k) {
    mx2 = __builtin_elementwise_max(mx2, ve[k]);
    xn2 = __builtin_elementwise_min(xn2, ve[k]);
  }
  const float mx = dpp_max16_f32(fmaxf(mx2.x, mx2.y));
  const float xn = dpp_min16_f32(fminf(xn2.x, xn2.y));

  // normalize constants (S-free): emin = exp(xn - mx); emax = exp(0) = 1
  const float LOG2E = 1.44269504089f;
  const float mxs  = mx * LOG2E;
  const float emin = HW_EXP2(fmaf(xn, LOG2E, -mxs));
  const float CA   = 1.0f / (1.0f - emin);
  const float CB   = fmaf(-emin, CA, 0.001f);
  const v2f L2E2 = {LOG2E, LOG2E};
  const v2f NMXS = {-mxs, -mxs};
  const v2f CA2 = {CA, CA}, CB2 = {CB, CB};

  // SINGLE pass: exp2 -> pn -> log2 -> packed f32 moment accumulation.
  // xh per pair = bb + compile-time-constant offset (exact), no serial chain.
  const float bb = (float)(4 * sub) * (1.0f / 512.0f);
  v2f u0 = {0, 0}, u1 = {0, 0}, u2 = {0, 0}, u3 = {0, 0}, u4 = {0, 0};
  v2f w0 = {0, 0}, w1 = {0, 0}, w2 = {0, 0};

#define GF_PAIR(j, h)                                                         \
  {                                                                           \
    const int   k   = 2 * (j) + (h);                                          \
    const float off = (float)(64 * (j) + 2 * (h)) * (1.0f / 512.0f);          \
    const v2f xh = {bb + off, bb + off + 0.001953125f};                       \
    const v2f xs = __builtin_elementwise_fma(ve[k], L2E2, NMXS);              \
    v2f e;                                                                    \
    e.x = HW_EXP2(xs.x);                                                      \
    e.y = HW_EXP2(xs.y);                                                      \
    const v2f pn = __builtin_elementwise_fma(e, CA2, CB2);                    \
    v2f l2;                                                                   \
    l2.x = HW_LOG2(pn.x);                                                     \
    l2.y = HW_LOG2(pn.y);                                                     \
    const v2f y2  = pn * pn;                                                  \
    const v2f y2l = y2 * l2;                                                  \
    const v2f x2  = xh * xh;                                                  \
    const v2f x3  = x2 * xh;                                                  \
    const v2f x4  = x2 * x2;                                                  \
    u0 += y2;                                                                 \
    u1 = __builtin_elementwise_fma(xh, y2, u1);                               \
    u2 = __builtin_elementwise_fma(x2, y2, u2);                               \
    u3 = __builtin_elementwise_fma(x3, y2, u3);                               \
    u4 = __builtin_elementwise_fma(x4, y2, u4);                               \
    w0 += y2l;                                                                \
    w1 = __builtin_elementwise_fma(xh, y2l, w1);                              \
    w2 = __builtin_elementwise_fma(x2, y2l, w2);                              \
  }

#pragma unroll
  for (int j = 0; j < 8; ++j) {
    GF_PAIR(j, 0)
    GF_PAIR(j, 1)
  }
#undef GF_PAIR

  // per-lane exact f64 hadd, then 16-lane DPP rotate-reduce in f64
  // (f64 REQUIRED here — see precision note above)
  const double d0 = dpp_sum16_f64((double)u0.x + (double)u0.y);
  const double d1 = dpp_sum16_f64((double)u1.x + (double)u1.y);
  const double d2 = dpp_sum16_f64((double)u2.x + (double)u2.y);
  const double d3 = dpp_sum16_f64((double)u3.x + (double)u3.y);
  const double d4 = dpp_sum16_f64((double)u4.x + (double)u4.y);
  const double e0 = dpp_sum16_f64((double)w0.x + (double)w0.y);
  const double e1 = dpp_sum16_f64((double)w1.x + (double)w1.y);
  const double e2 = dpp_sum16_f64((double)w2.x + (double)w2.y);

  if (sub == 0) {   // lanes 0,16,32,48 — one per row
    const double LN2D = 0.6931471805599453;
    // unscale by exact 512^k; apply ln2 to the log2-sums (one rounding each)
    const double s_y2    = d0;
    const double s_xy2   = d1 * 512.0;
    const double s_x2y2  = d2 * 262144.0;            // 512^2
    const double s_x3y2  = d3 * 134217728.0;         // 512^3
    const double s_x4y2  = d4 * 68719476736.0;       // 512^4
    const double s_y2l   = e0 * LN2D;
    const double s_xy2l  = (e1 * 512.0) * LN2D;
    const double s_x2y2l = (e2 * 262144.0) * LN2D;
    const double A2 = s_x2y2 * s_x2y2;
    double b_num = A2 * s_xy2l - s_y2 * s_x4y2 * s_xy2l
                 + s_xy2 * s_x4y2 * s_y2l + s_y2 * s_x3y2 * s_x2y2l
                 - s_x2y2 * s_x3y2 * s_y2l - s_xy2 * s_x2y2 * s_x2y2l;
    double c_num = s_x2y2l * s_xy2 * s_xy2 - s_xy2l * s_xy2 * s_x2y2
                 - s_x3y2 * s_y2l * s_xy2 + s_y2l * A2
                 - s_y2 * s_x2y2l * s_x2y2 + s_y2 * s_x3y2 * s_xy2l;
    if (fabs(c_num) < STAB) {
      c_num = (c_num > 0.0) ? STAB : ((c_num < 0.0) ? -STAB : 0.0);
    }
    const double mu = -b_num / (2.0 * c_num);
    const double c_din = s_x4y2 * s_xy2 * s_xy2
                       - 2.0 * s_xy2 * s_x2y2 * s_x3y2 + s_x2y2 * A2
                       - s_y2 * s_x4y2 * s_x2y2 + s_y2 * s_x3y2 * s_x3y2;
    double sigma = -0.5 * c_din / c_num;
    if (sigma < 1.0) sigma = 1.0;  // NaN stays NaN, matching jnp.where
    mu_out[row]  = (float)mu;
    sig_out[row] = (float)sigma;
  }
}

// ---------------------------------------------------------------------------
// Kernel 2: per-batch tridiagonal solve via parallel cyclic reduction, f32.
// (Byte-identical to round 24, which passed.)
// ---------------------------------------------------------------------------
__global__ __launch_bounds__(1024) void pcr_solve_kernel(
    const float* __restrict__ mu, const float* __restrict__ sigma,
    const float* __restrict__ w_comp, float* __restrict__ out) {
  __shared__ float A[2][XLEN], B[2][XLEN], C[2][XLEN], D[2][XLEN];
  const int i = threadIdx.x;
  const int g = blockIdx.x * XLEN + i;

  const float w = w_comp[0];
  const float offf  = -2.0f * w;
  const float mainw = (i == 0 || i == XLEN - 1) ? (2.0f * w) : (4.0f * w);
  const float sr = 1.0f / sigma[g];      // f32, matches reference
  const float bf = mainw + sr;           // f32 diag entry
  const float df = mu[g] * sr;           // f32 rhs

  A[0][i] = (i == 0) ? 0.0f : offf;
  C[0][i] = (i == XLEN - 1) ? 0.0f : offf;
  B[0][i] = bf;
  D[0][i] = df;
  __syncthreads();

  int cur = 0;
  for (int s = 1; s < XLEN; s <<= 1) {
    const float ai = A[cur][i], bi = B[cur][i], ci = C[cur][i], di = D[cur][i];
    float am = 0.0f, cm = 0.0f, dm = 0.0f, rm = 0.0f;
    float ap = 0.0f, cp = 0.0f, dp = 0.0f, rp = 0.0f;
    if (i >= s) {
      am = A[cur][i - s]; cm = C[cur][i - s]; dm = D[cur][i - s];
      rm = HW_RCP(B[cur][i - s]);
    }
    if (i + s < XLEN) {
      ap = A[cur][i + s]; cp = C[cur][i + s]; dp = D[cur][i + s];
      rp = HW_RCP(B[cur][i + s]);
    }
    const float k1 = ai * rm;   // rm/rp are 0 when guarded out
    const float k2 = ci * rp;
    const float nb = bi - k1 * cm - k2 * ap;
    const float nd = di - k1 * dm - k2 * dp;
    const int nxt = cur ^ 1;
    A[nxt][i] = -k1 * am;
    C[nxt][i] = -k2 * cp;
    B[nxt][i] = nb;
    D[nxt][i] = nd;
    __syncthreads();
    cur = nxt;
  }

  out[g] = D[cur][i] / B[cur][i];
}

extern "C" void kernel_launch(void* const* d_in, const int* in_sizes, int n_in,
                              void* d_out, int out_size, void* d_ws, size_t ws_size,
                              hipStream_t stream) {
  const float* x      = (const float*)d_in[0];
  const float* w_comp = (const float*)d_in[1];
  float* out = (float*)d_out;

  float* mu_ws  = (float*)d_ws;
  float* sig_ws = mu_ws + ROWS;

  gaus_fit_kernel<<<ROWS / 16, 256, 0, stream>>>(x, mu_ws, sig_ws);
  pcr_solve_kernel<<<BN, XLEN, 0, stream>>>(mu_ws, sig_ws, w_comp, out);
}